// Round 5
// baseline (193.240 us; speedup 1.0000x reference)
//
#include <hip/hip_runtime.h>

// CubePadding: x [B,6,C,H,W] fp32 -> out [B,6,C,H+2P,W+2P] fp32. Pure gather/copy.
// R6 (v8): homogeneous waves, v5 mistakes fixed.
//   Range A (interior, 94%): 1 lane per INPUT-aligned float4 (32/row, pow2 math).
//     Aligned dwordx4 load; shift the STORE ADDRESS (+2 floats) instead of the
//     data -> misaligned (8B-aligned) nontemporal dwordx4 store to out cols
//     4g+2..4g+5. Covers out cols 2..129 hole-free. No shfl, no branches.
//   Range B: (i) 1 thread per interior row fills out cols {0,1,130,131} via
//     direct lft/rgt maps; (ii) halo rows via gen_map gather (v5-verified).
//   Range B blocks are FIRST in the grid so gather stragglers overlap the
//   Range A stream (v5 put them last -> serialized tail).
// Face order: 0=back(fb) 1=down(fd) 2=front(ff) 3=left(fl) 4=right(fr) 5=top(ft)

typedef float f32x4 __attribute__((ext_vector_type(4)));
typedef f32x4 f32x4_a8 __attribute__((aligned(8)));   // 8B-aligned 16B access

constexpr int P = 2, B = 4, C = 64, H = 128, W = 128;
constexpr int Ho = H + 2 * P, Wo = W + 2 * P;   // 132, 132
constexpr int NV = Wo / 4;                      // 33 float4 groups per output row
constexpr int PLANES = B * 6 * C;               // 1536
constexpr int ROWS   = PLANES * H;              // 196,608 interior rows

// Range B part 1: one thread per interior row (edge cols)
constexpr int BLK_EDGE = ROWS / 256;            // 768 blocks (exact)
// Range B part 2: halo rows, one thread per output float4 group
constexpr int NHALO    = PLANES * 4 * NV;       // 202,752 = 792*256 (exact)
constexpr int BLK_HALO = NHALO / 256;           // 792 blocks
// Range A: interior copy, 32 lanes per input row
constexpr int BLK_A    = ROWS * 32 / 256;       // 24,576 blocks
constexpr int BLK_B    = BLK_EDGE + BLK_HALO;   // 1,560
constexpr int BLOCKS   = BLK_B + BLK_A;         // 26,136

// ---- halo source maps (verified in R0) ----
__device__ __forceinline__ void top_map(int f, int t, int w, int& sf, int& r, int& col) {
    switch (f) {
        case 0:  sf = 5; r = P - 1 - t; col = w;         break;
        case 1:  sf = 2; r = H - P + t; col = w;         break;
        case 2:  sf = 5; r = H - P + t; col = w;         break;
        case 3:  sf = 5; r = w;         col = t;         break;
        case 4:  sf = 5; r = w;         col = W - 1 - t; break;
        default: sf = 0; r = P - 1 - t; col = w;         break;
    }
}
__device__ __forceinline__ void bot_map(int f, int t, int w, int& sf, int& r, int& col) {
    switch (f) {
        case 0:  sf = 1; r = H - 1 - t; col = w;         break;
        case 1:  sf = 0; r = H - 1 - t; col = w;         break;
        case 2:  sf = 1; r = t;         col = w;         break;
        case 3:  sf = 1; r = w;         col = P - 1 - t; break;
        case 4:  sf = 1; r = w;         col = W - P + t; break;
        default: sf = 2; r = t;         col = w;         break;
    }
}
__device__ __forceinline__ void lft_map(int f, int h, int l, int& sf, int& r, int& col) {
    switch (f) {
        case 0:  sf = 4; r = h;         col = W - P + l; break;
        case 1:  sf = 3; r = H - 1 - l; col = h;         break;
        case 2:  sf = 3; r = h;         col = W - P + l; break;
        case 3:  sf = 0; r = h;         col = W - P + l; break;
        case 4:  sf = 2; r = h;         col = W - P + l; break;
        default: sf = 3; r = l;         col = h;         break;
    }
}
__device__ __forceinline__ void rgt_map(int f, int h, int rr, int& sf, int& r, int& col) {
    switch (f) {
        case 0:  sf = 3; r = h;          col = rr;        break;
        case 1:  sf = 4; r = H - P + rr; col = h;         break;
        case 2:  sf = 4; r = h;          col = rr;        break;
        case 3:  sf = 2; r = h;          col = rr;        break;
        case 4:  sf = 0; r = h;          col = rr;        break;
        default: sf = 4; r = P - 1 - rr; col = h;         break;
    }
}

// general per-element map: output (f,i,j) -> source (sf,r,col) within the same batch
__device__ __forceinline__ void gen_map(int f, int i, int j, int& sf, int& r, int& col) {
    bool in_h = (i >= P) && (i < H + P);
    bool in_w = (j >= P) && (j < W + P);
    if (in_h && in_w) {
        sf = f; r = i - P; col = j - P;
    } else if (!in_h) {
        int w = in_w ? (j - P) : (j < P ? 0 : W - 1);   // corners replicate strip edge
        if (i < P) top_map(f, i, w, sf, r, col);
        else       bot_map(f, i - H - P, w, sf, r, col);
    } else {
        if (j < P) lft_map(f, i - P, j,         sf, r, col);
        else       rgt_map(f, i - P, j - W - P, sf, r, col);
    }
}

__global__ __launch_bounds__(256) void cubepad_v8_kernel(const float* __restrict__ x,
                                                         float* __restrict__ out) {
    const int bid = blockIdx.x;
    const int tid = threadIdx.x;

    if (bid >= BLK_B) {
        // ---------------- Range A: branch-free interior copy ----------------
        const unsigned idx = (unsigned)(bid - BLK_B) * 256u + (unsigned)tid;
        const unsigned g   = idx & 31u;           // input float4 group (0..31)
        const unsigned row = idx >> 5;            // global input row
        const unsigned i   = row & (unsigned)(H - 1);
        const unsigned p   = row >> 7;            // plane index

        const f32x4 v = *(const f32x4*)(x + ((size_t)row << 7) + (g << 2));

        // out cols 4g+2 .. 4g+5 of output row i+P (8B-aligned 16B store)
        const size_t o = (size_t)p * (Ho * Wo) + (size_t)(i + P) * Wo + (g << 2) + P;
        __builtin_nontemporal_store(v, (f32x4_a8*)(out + o));
        return;
    }

    if (bid < BLK_EDGE) {
        // -------- Range B.1: interior-row edge cols {0,1} and {130,131} --------
        const unsigned row = (unsigned)bid * 256u + (unsigned)tid;  // [0, ROWS)
        const unsigned i   = row & (unsigned)(H - 1);               // face row
        const unsigned p   = row >> 7;
        const int f  = (int)((p >> 6) % 6u);
        const int bC = (int)(((p >> 6) / 6u) * (6u * C) + (p & 63u));

        int sf, r, col;
        float2 lv, rv;
        lft_map(f, (int)i, 0, sf, r, col);
        lv.x = x[((size_t)(bC + sf * C)) * (H * W) + ((size_t)r << 7) + col];
        lft_map(f, (int)i, 1, sf, r, col);
        lv.y = x[((size_t)(bC + sf * C)) * (H * W) + ((size_t)r << 7) + col];
        rgt_map(f, (int)i, 0, sf, r, col);
        rv.x = x[((size_t)(bC + sf * C)) * (H * W) + ((size_t)r << 7) + col];
        rgt_map(f, (int)i, 1, sf, r, col);
        rv.y = x[((size_t)(bC + sf * C)) * (H * W) + ((size_t)r << 7) + col];

        const size_t rb = (size_t)p * (Ho * Wo) + (size_t)(i + P) * Wo;
        *(float2*)(out + rb)            = lv;   // cols 0,1   (8B-aligned)
        *(float2*)(out + rb + (W + P))  = rv;   // cols 130,131 (8B-aligned)
        return;
    }

    // ---------------- Range B.2: halo rows (gen_map gather) ----------------
    const unsigned h = (unsigned)(bid - BLK_EDGE) * 256u + (unsigned)tid;  // [0, NHALO)
    const unsigned v    = h % (unsigned)NV;        // group within row
    const unsigned t2   = h / (unsigned)NV;
    const unsigned t    = t2 & 3u;                 // which halo row
    const unsigned p    = t2 >> 2;                 // plane
    const int i_out = (t < 2u) ? (int)t : (H + P + (int)t - 2);
    const int f  = (int)((p >> 6) % 6u);
    const int bC = (int)(((p >> 6) / 6u) * (6u * C) + (p & 63u));

    f32x4 val;
    #pragma unroll
    for (int e = 0; e < 4; ++e) {
        int sf, r, col;
        gen_map(f, i_out, (int)(4u * v) + e, sf, r, col);
        val[e] = x[((size_t)(bC + sf * C)) * (H * W) + ((size_t)r << 7) + col];
    }
    const size_t o = (size_t)p * (Ho * Wo) + (size_t)i_out * Wo + ((size_t)v << 2);
    __builtin_nontemporal_store(val, (f32x4*)(out + o));
}

extern "C" void kernel_launch(void* const* d_in, const int* in_sizes, int n_in,
                              void* d_out, int out_size, void* d_ws, size_t ws_size,
                              hipStream_t stream) {
    const float* x = (const float*)d_in[0];
    float* out = (float*)d_out;
    cubepad_v8_kernel<<<BLOCKS, 256, 0, stream>>>(x, out);
}

// Round 6
// 190.770 us; speedup vs baseline: 1.0129x; 1.0129x over previous
//
#include <hip/hip_runtime.h>

// CubePadding: x [B,6,C,H,W] fp32 -> out [B,6,C,H+2P,W+2P] fp32. Pure gather/copy.
// R7 (v9): v7's body (best: ~54us) + long contiguous per-block streams.
//   * 3267 blocks x 8 iterations x 256 threads = TOTAL_V exactly. Each block
//     processes 2048 CONSECUTIVE output float4 groups (32KB out, ~62 input rows):
//     few long sequential streams (fill-kernel regime) instead of 26k one-shot
//     blocks = thousands of interleaved 1KB streams (HBM locality thrash).
//   * fast path: ONE misaligned (8B-aligned) dwordx4 load; stores stay 16B-aligned
//     nontemporal (v8 proved misaligned NT stores cost +11MB RMW write traffic).
//   * v=0/v=32 interior lanes: direct lft/rgt maps; halo rows (3%): gen_map.
//   * per-iter index math is incremental (v += 25 mod 33, t1 += 7/8) -- only one
//     magic-divide pair (t1 -> i, rest) left per iteration.
// Face order: 0=back(fb) 1=down(fd) 2=front(ff) 3=left(fl) 4=right(fr) 5=top(ft)

typedef float f32x4 __attribute__((ext_vector_type(4)));
typedef f32x4 f32x4_u __attribute__((aligned(4)));   // permits 4B-aligned 16B loads

constexpr int P = 2, B = 4, C = 64, H = 128, W = 128;
constexpr int Ho = H + 2 * P, Wo = W + 2 * P;   // 132, 132
constexpr int NV = Wo / 4;                      // 33 float4 groups per output row
constexpr int TOTAL_V = B * 6 * C * Ho * NV;    // 6,690,816 output float4 groups
constexpr int ITER   = 8;
constexpr int CHUNK  = ITER * 256;              // 2048 groups per block (contiguous)
constexpr int BLOCKS = TOTAL_V / CHUNK;         // 3267 (exact)

// ---- halo source maps (verified in R0) ----
__device__ __forceinline__ void top_map(int f, int t, int w, int& sf, int& r, int& col) {
    switch (f) {
        case 0:  sf = 5; r = P - 1 - t; col = w;         break;
        case 1:  sf = 2; r = H - P + t; col = w;         break;
        case 2:  sf = 5; r = H - P + t; col = w;         break;
        case 3:  sf = 5; r = w;         col = t;         break;
        case 4:  sf = 5; r = w;         col = W - 1 - t; break;
        default: sf = 0; r = P - 1 - t; col = w;         break;
    }
}
__device__ __forceinline__ void bot_map(int f, int t, int w, int& sf, int& r, int& col) {
    switch (f) {
        case 0:  sf = 1; r = H - 1 - t; col = w;         break;
        case 1:  sf = 0; r = H - 1 - t; col = w;         break;
        case 2:  sf = 1; r = t;         col = w;         break;
        case 3:  sf = 1; r = w;         col = P - 1 - t; break;
        case 4:  sf = 1; r = w;         col = W - P + t; break;
        default: sf = 2; r = t;         col = w;         break;
    }
}
__device__ __forceinline__ void lft_map(int f, int h, int l, int& sf, int& r, int& col) {
    switch (f) {
        case 0:  sf = 4; r = h;         col = W - P + l; break;
        case 1:  sf = 3; r = H - 1 - l; col = h;         break;
        case 2:  sf = 3; r = h;         col = W - P + l; break;
        case 3:  sf = 0; r = h;         col = W - P + l; break;
        case 4:  sf = 2; r = h;         col = W - P + l; break;
        default: sf = 3; r = l;         col = h;         break;
    }
}
__device__ __forceinline__ void rgt_map(int f, int h, int rr, int& sf, int& r, int& col) {
    switch (f) {
        case 0:  sf = 3; r = h;          col = rr;        break;
        case 1:  sf = 4; r = H - P + rr; col = h;         break;
        case 2:  sf = 4; r = h;          col = rr;        break;
        case 3:  sf = 2; r = h;          col = rr;        break;
        case 4:  sf = 0; r = h;          col = rr;        break;
        default: sf = 4; r = P - 1 - rr; col = h;         break;
    }
}

// general per-element map: output (f,i,j) -> source (sf,r,col) within the same batch
__device__ __forceinline__ void gen_map(int f, int i, int j, int& sf, int& r, int& col) {
    bool in_h = (i >= P) && (i < H + P);
    bool in_w = (j >= P) && (j < W + P);
    if (in_h && in_w) {
        sf = f; r = i - P; col = j - P;
    } else if (!in_h) {
        int w = in_w ? (j - P) : (j < P ? 0 : W - 1);   // corners replicate strip edge
        if (i < P) top_map(f, i, w, sf, r, col);
        else       bot_map(f, i - H - P, w, sf, r, col);
    } else {
        if (j < P) lft_map(f, i - P, j,         sf, r, col);
        else       rgt_map(f, i - P, j - W - P, sf, r, col);
    }
}

__global__ __launch_bounds__(256) void cubepad_v9_kernel(const float* __restrict__ x,
                                                         float* __restrict__ out) {
    const unsigned idx0 = (unsigned)blockIdx.x * (unsigned)CHUNK + threadIdx.x;

    unsigned v  = idx0 % (unsigned)NV;   // float4 group within output row
    unsigned t1 = idx0 / (unsigned)NV;   // global output row

    #pragma unroll
    for (int it = 0; it < ITER; ++it) {
        const unsigned i    = t1 % (unsigned)Ho;   // output row within plane
        const unsigned rest = t1 / (unsigned)Ho;   // (b*6 + f)*C + c
        const int f  = (int)((rest >> 6) % 6u);
        const int bC = (int)(((rest >> 6) / 6u) * (6u * C) + (rest & 63u));

        const size_t out_off = (size_t)t1 * Wo + 4u * v;
        const float* plane = x + ((size_t)(bC + f * C)) * (H * W);

        f32x4 val;

        if (i >= P && i < H + P) {
            const float* rowp = plane + (size_t)(i - P) * W;
            if (v - 1u < (unsigned)(NV - 2)) {
                // interior: src cols 4v-2 .. 4v+1, one 16B load at 8B-aligned addr
                val = *(const f32x4_u*)(rowp + 4u * v - P);
            } else if (v == 0u) {
                const float2 t = *(const float2*)(rowp);        // in cols 0,1
                int sf, r, col;
                lft_map(f, (int)i - P, 0, sf, r, col);
                val[0] = x[((size_t)(bC + sf * C)) * (H * W) + (size_t)r * W + col];
                lft_map(f, (int)i - P, 1, sf, r, col);
                val[1] = x[((size_t)(bC + sf * C)) * (H * W) + (size_t)r * W + col];
                val[2] = t.x; val[3] = t.y;
            } else {
                const float2 t = *(const float2*)(rowp + (W - P));  // in cols 126,127
                val[0] = t.x; val[1] = t.y;
                int sf, r, col;
                rgt_map(f, (int)i - P, 0, sf, r, col);
                val[2] = x[((size_t)(bC + sf * C)) * (H * W) + (size_t)r * W + col];
                rgt_map(f, (int)i - P, 1, sf, r, col);
                val[3] = x[((size_t)(bC + sf * C)) * (H * W) + (size_t)r * W + col];
            }
        } else {
            // halo rows (i in {0,1,130,131}): full gather
            #pragma unroll
            for (int e = 0; e < 4; ++e) {
                int sf, r, col;
                gen_map(f, (int)i, (int)(4u * v) + e, sf, r, col);
                val[e] = x[((size_t)(bC + sf * C)) * (H * W) + (size_t)r * W + col];
            }
        }

        __builtin_nontemporal_store(val, (f32x4*)(out + out_off));

        // incremental index update: idx += 256 => v += 256%33 (=25), t1 += 7 (+carry)
        v += 25u;
        if (v >= (unsigned)NV) { v -= (unsigned)NV; t1 += 8u; }
        else                   { t1 += 7u; }
    }
}

extern "C" void kernel_launch(void* const* d_in, const int* in_sizes, int n_in,
                              void* d_out, int out_size, void* d_ws, size_t ws_size,
                              hipStream_t stream) {
    const float* x = (const float*)d_in[0];
    float* out = (float*)d_out;
    cubepad_v9_kernel<<<BLOCKS, 256, 0, stream>>>(x, out);
}

// Round 7
// 186.549 us; speedup vs baseline: 1.0359x; 1.0226x over previous
//
#include <hip/hip_runtime.h>

// CubePadding: x [B,6,C,H,W] fp32 -> out [B,6,C,H+2P,W+2P] fp32. Pure gather/copy.
// R8 (v10): aligned-both-sides via LDS, without v5's three mistakes.
//   Interior: 1 block per 8-row band. Phase 1: 256 ALIGNED dwordx4 loads -> 4KB
//   LDS. One barrier. Phase 2: 264 ALIGNED, hole-free 16B nt stores per band
//   (interior groups ds_read the +2-float shift, 8B-aligned = free in LDS;
//   g=0/g=32 splice 2 direct lft/rgt gathers). No shfl, no store holes.
//   Halo rows: v8-verified gen_map path, placed FIRST in the grid (no tail).
//   vs v7 (best, ~54us): removes misaligned global loads (every 4th split a
//   64B line) and removes divergent edge gathers from 97% of waves.
// Face order: 0=back(fb) 1=down(fd) 2=front(ff) 3=left(fl) 4=right(fr) 5=top(ft)

typedef float f32x4 __attribute__((ext_vector_type(4)));
typedef f32x4 f32x4_a8 __attribute__((aligned(8)));   // 8B-aligned 16B LDS read

constexpr int P = 2, B = 4, C = 64, H = 128, W = 128;
constexpr int Ho = H + 2 * P, Wo = W + 2 * P;   // 132, 132
constexpr int NV = Wo / 4;                      // 33 float4 groups per output row
constexpr int PLANES = B * 6 * C;               // 1536

constexpr int NHALO    = PLANES * 4 * NV;       // 202,752 = 792*256 (exact)
constexpr int BLK_HALO = NHALO / 256;           // 792 blocks (first in grid)
constexpr int BANDS    = PLANES * (H / 8);      // 24,576 interior blocks
constexpr int BLOCKS   = BLK_HALO + BANDS;      // 25,368

// ---- halo source maps (verified R0; re-verified by v8 absmax=0) ----
__device__ __forceinline__ void top_map(int f, int t, int w, int& sf, int& r, int& col) {
    switch (f) {
        case 0:  sf = 5; r = P - 1 - t; col = w;         break;
        case 1:  sf = 2; r = H - P + t; col = w;         break;
        case 2:  sf = 5; r = H - P + t; col = w;         break;
        case 3:  sf = 5; r = w;         col = t;         break;
        case 4:  sf = 5; r = w;         col = W - 1 - t; break;
        default: sf = 0; r = P - 1 - t; col = w;         break;
    }
}
__device__ __forceinline__ void bot_map(int f, int t, int w, int& sf, int& r, int& col) {
    switch (f) {
        case 0:  sf = 1; r = H - 1 - t; col = w;         break;
        case 1:  sf = 0; r = H - 1 - t; col = w;         break;
        case 2:  sf = 1; r = t;         col = w;         break;
        case 3:  sf = 1; r = w;         col = P - 1 - t; break;
        case 4:  sf = 1; r = w;         col = W - P + t; break;
        default: sf = 2; r = t;         col = w;         break;
    }
}
__device__ __forceinline__ void lft_map(int f, int h, int l, int& sf, int& r, int& col) {
    switch (f) {
        case 0:  sf = 4; r = h;         col = W - P + l; break;
        case 1:  sf = 3; r = H - 1 - l; col = h;         break;
        case 2:  sf = 3; r = h;         col = W - P + l; break;
        case 3:  sf = 0; r = h;         col = W - P + l; break;
        case 4:  sf = 2; r = h;         col = W - P + l; break;
        default: sf = 3; r = l;         col = h;         break;
    }
}
__device__ __forceinline__ void rgt_map(int f, int h, int rr, int& sf, int& r, int& col) {
    switch (f) {
        case 0:  sf = 3; r = h;          col = rr;        break;
        case 1:  sf = 4; r = H - P + rr; col = h;         break;
        case 2:  sf = 4; r = h;          col = rr;        break;
        case 3:  sf = 2; r = h;          col = rr;        break;
        case 4:  sf = 0; r = h;          col = rr;        break;
        default: sf = 4; r = P - 1 - rr; col = h;         break;
    }
}

// general per-element map (halo rows only)
__device__ __forceinline__ void gen_map(int f, int i, int j, int& sf, int& r, int& col) {
    bool in_h = (i >= P) && (i < H + P);
    bool in_w = (j >= P) && (j < W + P);
    if (in_h && in_w) {
        sf = f; r = i - P; col = j - P;
    } else if (!in_h) {
        int w = in_w ? (j - P) : (j < P ? 0 : W - 1);   // corners replicate strip edge
        if (i < P) top_map(f, i, w, sf, r, col);
        else       bot_map(f, i - H - P, w, sf, r, col);
    } else {
        if (j < P) lft_map(f, i - P, j,         sf, r, col);
        else       rgt_map(f, i - P, j - W - P, sf, r, col);
    }
}

__global__ __launch_bounds__(256) void cubepad_v10_kernel(const float* __restrict__ x,
                                                          float* __restrict__ out) {
    __shared__ float lds[8 * W];   // 4 KB: 8 input rows
    const int bid = blockIdx.x;
    const int tid = threadIdx.x;

    if (bid >= BLK_HALO) {
        // ---------------- interior band: 8 input rows ----------------
        const int band = bid - BLK_HALO;
        const int p    = band >> 4;               // plane (b*6+f)*C + c
        const int r0   = (band & 15) << 3;        // first input row of band
        const int f    = (p >> 6) % 6;
        const int bC   = ((p >> 6) / 6) * (6 * C) + (p & 63);
        const float* plane = x + (size_t)p * (H * W);

        // phase 1: 256 aligned dwordx4 loads -> LDS (row r cols 4g..4g+3)
        {
            const int r = tid >> 5, g = tid & 31;
            const f32x4 v = *(const f32x4*)(plane + ((size_t)(r0 + r) << 7) + (g << 2));
            *(f32x4*)(&lds[tid << 2]) = v;        // lds[r*128 + 4g + e]
        }
        __syncthreads();

        // phase 2: 264 aligned, hole-free 16B stores (rows r0..r0+7, groups 0..32)
        const size_t ob = (size_t)p * (Ho * Wo);
        for (int m = tid; m < 8 * NV; m += 256) {
            const unsigned r = (unsigned)m / 33u;     // band-local row 0..7
            const int g = m - (int)(r * 33u);         // group 0..32
            const int i = r0 + (int)r;                // face row
            f32x4 o;
            if (g == 0) {
                int sf, rr, cc;
                lft_map(f, i, 0, sf, rr, cc);
                o[0] = x[((size_t)(bC + sf * C)) * (H * W) + ((size_t)rr << 7) + cc];
                lft_map(f, i, 1, sf, rr, cc);
                o[1] = x[((size_t)(bC + sf * C)) * (H * W) + ((size_t)rr << 7) + cc];
                o[2] = lds[(r << 7) + 0];
                o[3] = lds[(r << 7) + 1];
            } else if (g == NV - 1) {
                o[0] = lds[(r << 7) + 126];
                o[1] = lds[(r << 7) + 127];
                int sf, rr, cc;
                rgt_map(f, i, 0, sf, rr, cc);
                o[2] = x[((size_t)(bC + sf * C)) * (H * W) + ((size_t)rr << 7) + cc];
                rgt_map(f, i, 1, sf, rr, cc);
                o[3] = x[((size_t)(bC + sf * C)) * (H * W) + ((size_t)rr << 7) + cc];
            } else {
                // out cols 4g..4g+3 = in cols 4g-2..4g+1 (8B-aligned LDS read)
                o = *(const f32x4_a8*)(&lds[(r << 7) + (g << 2) - 2]);
            }
            __builtin_nontemporal_store(
                o, (f32x4*)(out + ob + (size_t)(i + P) * Wo + ((size_t)g << 2)));
        }
        return;
    }

    // ---------------- halo rows (gen_map gather; v8-verified) ----------------
    const unsigned h  = (unsigned)bid * 256u + (unsigned)tid;   // [0, NHALO)
    const unsigned v  = h % (unsigned)NV;          // group within row
    const unsigned t2 = h / (unsigned)NV;
    const unsigned t  = t2 & 3u;                   // which halo row
    const unsigned p  = t2 >> 2;                   // plane
    const int i_out = (t < 2u) ? (int)t : (H + P + (int)t - 2);
    const int f  = (int)((p >> 6) % 6u);
    const int bC = (int)(((p >> 6) / 6u) * (6u * C) + (p & 63u));

    f32x4 val;
    #pragma unroll
    for (int e = 0; e < 4; ++e) {
        int sf, r, col;
        gen_map(f, i_out, (int)(4u * v) + e, sf, r, col);
        val[e] = x[((size_t)(bC + sf * C)) * (H * W) + ((size_t)r << 7) + col];
    }
    const size_t o = (size_t)p * (Ho * Wo) + (size_t)i_out * Wo + ((size_t)v << 2);
    __builtin_nontemporal_store(val, (f32x4*)(out + o));
}

extern "C" void kernel_launch(void* const* d_in, const int* in_sizes, int n_in,
                              void* d_out, int out_size, void* d_ws, size_t ws_size,
                              hipStream_t stream) {
    const float* x = (const float*)d_in[0];
    float* out = (float*)d_out;
    cubepad_v10_kernel<<<BLOCKS, 256, 0, stream>>>(x, out);
}